// Round 15
// baseline (190.371 us; speedup 1.0000x reference)
//
#include <hip/hip_runtime.h>
#include <hip/hip_bf16.h>

#define B_  4
#define C_  640
#define H_  64
#define W_  64
#define G_  16          // channel groups (one wave each)
#define CPG 40          // channels per wave: G_*CPG == C_
#define NT  1024

__device__ __forceinline__ unsigned short f2bf(float f) {
    __hip_bfloat16 h = __float2bfloat16(f);
    return __builtin_bit_cast(unsigned short, h);
}

// Accumulate one Fwarp row (4 px in r) against ft4 into a[12] (3 col-offsets x 4 px).
__device__ __forceinline__ void row_acc(const float4 ft4, const float4 r,
                                        const int l16, float* a) {
    const float pw = __shfl_up(r.w, 1, 64);     // lane l-1's elem 3
    const float nx = __shfl_down(r.x, 1, 64);   // lane l+1's elem 0
    const float vL0 = (l16 == 0)  ? r.x : pw;   // col 0 replicate
    const float vR3 = (l16 == 15) ? r.w : nx;   // col 63 replicate
    a[0]  = fmaf(ft4.x, vL0, a[0]);             // cc = col-1
    a[1]  = fmaf(ft4.y, r.x, a[1]);
    a[2]  = fmaf(ft4.z, r.y, a[2]);
    a[3]  = fmaf(ft4.w, r.z, a[3]);
    a[4]  = fmaf(ft4.x, r.x, a[4]);             // cc = center
    a[5]  = fmaf(ft4.y, r.y, a[5]);
    a[6]  = fmaf(ft4.z, r.z, a[6]);
    a[7]  = fmaf(ft4.w, r.w, a[7]);
    a[8]  = fmaf(ft4.x, r.y, a[8]);             // cc = col+1
    a[9]  = fmaf(ft4.y, r.z, a[9]);
    a[10] = fmaf(ft4.z, r.w, a[10]);
    a[11] = fmaf(ft4.w, vR3, a[11]);
}

// Weighted sum of one Fwarp row into fwv[4]; at = attn[4px][9], r3 = 3*row.
__device__ __forceinline__ void row_fw(const float4 r, const int l16,
                                       const float* at, const int r3, float* fwv) {
    const float pw = __shfl_up(r.w, 1, 64);
    const float nx = __shfl_down(r.x, 1, 64);
    const float vL0 = (l16 == 0)  ? r.x : pw;
    const float vR3 = (l16 == 15) ? r.w : nx;
    fwv[0] += at[0*9+r3]*vL0 + at[0*9+r3+1]*r.x + at[0*9+r3+2]*r.y;
    fwv[1] += at[1*9+r3]*r.x + at[1*9+r3+1]*r.y + at[1*9+r3+2]*r.z;
    fwv[2] += at[2*9+r3]*r.y + at[2*9+r3+1]*r.z + at[2*9+r3+2]*r.w;
    fwv[3] += at[3*9+r3]*r.z + at[3*9+r3+1]*r.w + at[3*9+r3+2]*vR3;
}

__global__ __launch_bounds__(NT, 4) void nca_fused(
    const float* __restrict__ Ft,
    const float* __restrict__ Fwp,
    const float* __restrict__ mask,
    const float* __restrict__ cw,
    const float* __restrict__ cb,
    float* __restrict__ out)
{
    __shared__ float lds_cw[2 * C_];        // 5 KB
    __shared__ float lds_msk[3][W_];        // 0.75 KB
    __shared__ float lds_sim[G_][W_][9];    // 36 KB
    __shared__ float lds_PT[G_][4][W_];     // 16 KB
    __shared__ float lds_attn[W_][9];       // 2.25 KB
    __shared__ float lds_Pf[4][W_];         // 1 KB
    __shared__ float lds_lam[W_];           // 0.25 KB
    // ~61.5 KB

    const int t   = threadIdx.x;
    const int l   = t & 63;
    const int g   = t >> 6;        // wave id = channel group
    const int sub = l >> 4;        // channel subgroup 0..3
    const int l16 = l & 15;
    const int w0  = l16 * 4;       // first pixel column of this lane

    // XCD-aware swizzle: XCD x owns rows [x*8, x*8+8) for all batches.
    const int n    = blockIdx.x + gridDim.x * blockIdx.y;
    const int slot = n >> 3;
    const int h = (n & 7) * 8 + (slot & 7);
    const int b = slot >> 3;

    const int hm = (h > 0) ? (h - 1) : 0;
    const int hp = (h < H_ - 1) ? (h + 1) : (H_ - 1);
    const size_t cs = (size_t)H_ * W_;
    const int c0 = g * CPG;

    for (int i = t; i < 2 * C_; i += NT) lds_cw[i] = cw[i];
    if (t < 3 * W_) {
        const int r = t >> 6, col = t & 63;
        const int row = (r == 0) ? hm : ((r == 1) ? h : hp);
        lds_msk[r][col] = mask[((size_t)b * H_ + row) * W_ + col];
    }
    __syncthreads();

    const size_t base = (size_t)(b * C_ + c0) * H_;
    const size_t lo   = (size_t)sub * cs + w0;
    const float* ftp = Ft  + (base + h ) * W_ + lo;
    const float* q0p = Fwp + (base + hm) * W_ + lo;
    const float* q1p = Fwp + (base + h ) * W_ + lo;
    const float* q2p = Fwp + (base + hp) * W_ + lo;

    // ---- Pass A + P/T fused: ONE streaming walk ---------------------------
    // Center Fwarp row carried to Pass BC as packed bf16 in registers:
    // pk[2*it] = {r1.x, r1.y}, pk[2*it+1] = {r1.z, r1.w}. Fully unrolled ->
    // static indexing (rule #20), 20 VGPRs live across the softmax phase.
    float acc[36], Pp[12], T4[4];
    unsigned int pk[2 * (CPG / 4)];
    #pragma unroll
    for (int i = 0; i < 36; ++i) acc[i] = 0.f;
    #pragma unroll
    for (int i = 0; i < 12; ++i) Pp[i] = 0.f;
    #pragma unroll
    for (int i = 0; i < 4; ++i) T4[i] = 0.f;

    #pragma unroll
    for (int k = 0; k < CPG; k += 4) {
        const int it = k >> 2;
        const size_t off = (size_t)k * cs;
        const float4 ft4 = *(const float4*)(ftp + off);
        const float4 r0  = *(const float4*)(q0p + off);
        const float4 r1  = *(const float4*)(q1p + off);
        const float4 r2  = *(const float4*)(q2p + off);
        row_acc(ft4, r0, l16, &acc[0]);
        row_acc(ft4, r1, l16, &acc[12]);
        row_acc(ft4, r2, l16, &acc[24]);
        pk[2*it]   = (unsigned)f2bf(r1.x) | ((unsigned)f2bf(r1.y) << 16);
        pk[2*it+1] = (unsigned)f2bf(r1.z) | ((unsigned)f2bf(r1.w) << 16);
        const int c = c0 + k + sub;
        const float wF = lds_cw[c];
        const float wT = lds_cw[C_ + c];
        Pp[0] = fmaf(wF, r0.x, Pp[0]); Pp[1]  = fmaf(wF, r0.y, Pp[1]);
        Pp[2] = fmaf(wF, r0.z, Pp[2]); Pp[3]  = fmaf(wF, r0.w, Pp[3]);
        Pp[4] = fmaf(wF, r1.x, Pp[4]); Pp[5]  = fmaf(wF, r1.y, Pp[5]);
        Pp[6] = fmaf(wF, r1.z, Pp[6]); Pp[7]  = fmaf(wF, r1.w, Pp[7]);
        Pp[8] = fmaf(wF, r2.x, Pp[8]); Pp[9]  = fmaf(wF, r2.y, Pp[9]);
        Pp[10]= fmaf(wF, r2.z, Pp[10]);Pp[11] = fmaf(wF, r2.w, Pp[11]);
        T4[0] = fmaf(wT, ft4.x, T4[0]); T4[1] = fmaf(wT, ft4.y, T4[1]);
        T4[2] = fmaf(wT, ft4.z, T4[2]); T4[3] = fmaf(wT, ft4.w, T4[3]);
    }

    // reduce the 4 channel-subgroups (lanes l, l^16, l^32, l^48)
    #pragma unroll
    for (int i = 0; i < 36; ++i) {
        acc[i] += __shfl_xor(acc[i], 16, 64);
        acc[i] += __shfl_xor(acc[i], 32, 64);
    }
    #pragma unroll
    for (int i = 0; i < 12; ++i) {
        Pp[i] += __shfl_xor(Pp[i], 16, 64);
        Pp[i] += __shfl_xor(Pp[i], 32, 64);
    }
    #pragma unroll
    for (int i = 0; i < 4; ++i) {
        T4[i] += __shfl_xor(T4[i], 16, 64);
        T4[i] += __shfl_xor(T4[i], 32, 64);
    }

    // STATIC-index LDS write (rule #20: px is an unroll constant)
    if (l < 16) {
        #pragma unroll
        for (int px = 0; px < 4; ++px) {
            #pragma unroll
            for (int r = 0; r < 3; ++r) {
                #pragma unroll
                for (int cc = 0; cc < 3; ++cc)
                    lds_sim[g][w0 + px][r * 3 + cc] = acc[r * 12 + cc * 4 + px];
                lds_PT[g][r][w0 + px] = Pp[r * 4 + px];
            }
            lds_PT[g][3][w0 + px] = T4[px];
        }
    }
    __syncthreads();

    // ---- reduce across waves + mask; P/T reduce in parallel threads -------
    if (t < W_ * 9) {
        const int ww = t / 9, q = t % 9;
        float s = 0.f;
        #pragma unroll
        for (int gg = 0; gg < G_; ++gg) s += lds_sim[gg][ww][q];
        s *= 0.03952847075210474f;          // 1/sqrt(640)
        const int r = q / 3, j = q % 3;
        int col = ww + j - 1;
        col = col < 0 ? 0 : (col > W_ - 1 ? W_ - 1 : col);
        if (lds_msk[r][col] == 1.0f) s = -1e9f;
        lds_attn[ww][q] = s;
    } else if (t >= 640 && t < 640 + 256) {
        const int idx = t - 640;
        const int r = idx >> 6, ww = idx & 63;
        float s = 0.f;
        #pragma unroll
        for (int gg = 0; gg < G_; ++gg) s += lds_PT[gg][r][ww];
        lds_Pf[r][ww] = s;
    }
    __syncthreads();

    // ---- softmax per pixel + lambda via P-trick ---------------------------
    if (t < W_) {
        float v[9];
        float mx = -3e38f;
        bool valid = false;
        #pragma unroll
        for (int q = 0; q < 9; ++q) {
            v[q] = lds_attn[t][q];
            if (v[q] > -5e8f) valid = true;
            mx = fmaxf(mx, v[q]);
        }
        float a9[9];
        if (!valid) {
            #pragma unroll
            for (int q = 0; q < 9; ++q) a9[q] = 0.f;
        } else {
            float sum = 0.f;
            #pragma unroll
            for (int q = 0; q < 9; ++q) { a9[q] = expf(v[q] - mx); sum += a9[q]; }
            const float inv = 1.f / sum;
            #pragma unroll
            for (int q = 0; q < 9; ++q) a9[q] *= inv;
        }
        #pragma unroll
        for (int q = 0; q < 9; ++q) lds_attn[t][q] = a9[q];

        float lamF = 0.f;
        #pragma unroll
        for (int r = 0; r < 3; ++r)
            #pragma unroll
            for (int j = 0; j < 3; ++j) {
                int col = t + j - 1;
                col = col < 0 ? 0 : (col > W_ - 1 ? W_ - 1 : col);
                lamF = fmaf(a9[r * 3 + j], lds_Pf[r][col], lamF);
            }
        const float d = lds_Pf[3][t] + lamF + cb[0];
        lds_lam[t] = 1.f / (1.f + expf(-d));
    }
    __syncthreads();

    // ---- Pass BC: fwv + blend + store (3 streams + reg-resident f1) -------
    // Reverse channel order: A-walk's tail channels are still L2-resident.
    float at[36];
    #pragma unroll
    for (int px = 0; px < 4; ++px)
        #pragma unroll
        for (int q = 0; q < 9; ++q) at[px * 9 + q] = lds_attn[w0 + px][q];
    float lam4[4], oml4[4];
    #pragma unroll
    for (int px = 0; px < 4; ++px) {
        lam4[px] = lds_lam[w0 + px];
        oml4[px] = 1.f - lam4[px];
    }

    float* outp = out + (base + h) * W_ + lo;
    #pragma unroll
    for (int k = CPG - 4; k >= 0; k -= 4) {
        const int it = k >> 2;
        const size_t off = (size_t)k * cs;
        const float4 ft4 = *(const float4*)(ftp + off);
        const float4 r0  = *(const float4*)(q0p + off);
        const float4 r2  = *(const float4*)(q2p + off);
        float4 r1;                              // unpack bf16 center row
        r1.x = __builtin_bit_cast(float, pk[2*it] << 16);
        r1.y = __builtin_bit_cast(float, pk[2*it] & 0xffff0000u);
        r1.z = __builtin_bit_cast(float, pk[2*it+1] << 16);
        r1.w = __builtin_bit_cast(float, pk[2*it+1] & 0xffff0000u);
        float fwv[4] = {0.f, 0.f, 0.f, 0.f};
        row_fw(r0, l16, at, 0, fwv);
        row_fw(r1, l16, at, 3, fwv);
        row_fw(r2, l16, at, 6, fwv);
        float4 o;
        o.x = lam4[0] * ft4.x + oml4[0] * fwv[0];
        o.y = lam4[1] * ft4.y + oml4[1] * fwv[1];
        o.z = lam4[2] * ft4.z + oml4[2] * fwv[2];
        o.w = lam4[3] * ft4.w + oml4[3] * fwv[3];
        *(float4*)(outp + off) = o;
    }
}

extern "C" void kernel_launch(void* const* d_in, const int* in_sizes, int n_in,
                              void* d_out, int out_size, void* d_ws, size_t ws_size,
                              hipStream_t stream) {
    const float* Ft   = (const float*)d_in[0];
    const float* Fwp  = (const float*)d_in[1];
    const float* mask = (const float*)d_in[2];
    const float* cw   = (const float*)d_in[3];
    const float* cb   = (const float*)d_in[4];
    float* out = (float*)d_out;

    dim3 grid(H_, B_);   // 256 blocks == 256 CUs
    dim3 block(NT);
    nca_fused<<<grid, block, 0, stream>>>(Ft, Fwp, mask, cw, cb, out);
}

// Round 16
// 52.852 us; speedup vs baseline: 3.6020x; 3.6020x over previous
//
#include <hip/hip_runtime.h>

#define B_  4
#define C_  640
#define H_  64
#define W_  64
#define G_  16          // channel groups (one wave each)
#define CPG 40          // channels per wave: G_*CPG == C_
#define NT  1024

// Accumulate one Fwarp row (4 px in r) against ft4 into a[12] (3 col-offsets x 4 px).
__device__ __forceinline__ void row_acc(const float4 ft4, const float4 r,
                                        const int l16, float* a) {
    const float pw = __shfl_up(r.w, 1, 64);     // lane l-1's elem 3
    const float nx = __shfl_down(r.x, 1, 64);   // lane l+1's elem 0
    const float vL0 = (l16 == 0)  ? r.x : pw;   // col 0 replicate
    const float vR3 = (l16 == 15) ? r.w : nx;   // col 63 replicate
    a[0]  = fmaf(ft4.x, vL0, a[0]);             // cc = col-1
    a[1]  = fmaf(ft4.y, r.x, a[1]);
    a[2]  = fmaf(ft4.z, r.y, a[2]);
    a[3]  = fmaf(ft4.w, r.z, a[3]);
    a[4]  = fmaf(ft4.x, r.x, a[4]);             // cc = center
    a[5]  = fmaf(ft4.y, r.y, a[5]);
    a[6]  = fmaf(ft4.z, r.z, a[6]);
    a[7]  = fmaf(ft4.w, r.w, a[7]);
    a[8]  = fmaf(ft4.x, r.y, a[8]);             // cc = col+1
    a[9]  = fmaf(ft4.y, r.z, a[9]);
    a[10] = fmaf(ft4.z, r.w, a[10]);
    a[11] = fmaf(ft4.w, vR3, a[11]);
}

// Weighted sum of one Fwarp row into fwv[4]; at = attn[4px][9], r3 = 3*row.
__device__ __forceinline__ void row_fw(const float4 r, const int l16,
                                       const float* at, const int r3, float* fwv) {
    const float pw = __shfl_up(r.w, 1, 64);
    const float nx = __shfl_down(r.x, 1, 64);
    const float vL0 = (l16 == 0)  ? r.x : pw;
    const float vR3 = (l16 == 15) ? r.w : nx;
    fwv[0] += at[0*9+r3]*vL0 + at[0*9+r3+1]*r.x + at[0*9+r3+2]*r.y;
    fwv[1] += at[1*9+r3]*r.x + at[1*9+r3+1]*r.y + at[1*9+r3+2]*r.z;
    fwv[2] += at[2*9+r3]*r.y + at[2*9+r3+1]*r.z + at[2*9+r3+2]*r.w;
    fwv[3] += at[3*9+r3]*r.z + at[3*9+r3+1]*r.w + at[3*9+r3+2]*vR3;
}

__global__ __launch_bounds__(NT)
__attribute__((amdgpu_waves_per_eu(4, 4)))   // grid==1 block/CU: occupancy can
                                             // never exceed 4 waves/EU, so let
                                             // the allocator use up to 128 VGPR
void nca_fused(
    const float* __restrict__ Ft,
    const float* __restrict__ Fwp,
    const float* __restrict__ mask,
    const float* __restrict__ cw,
    const float* __restrict__ cb,
    float* __restrict__ out)
{
    __shared__ float lds_cw[2 * C_];        // 5 KB
    __shared__ float lds_msk[3][W_];        // 0.75 KB
    __shared__ float lds_sim[G_][W_][9];    // 36 KB
    __shared__ float lds_PT[G_][4][W_];     // 16 KB
    __shared__ float lds_attn[W_][9];       // 2.25 KB
    __shared__ float lds_Pf[4][W_];         // 1 KB
    __shared__ float lds_lam[W_];           // 0.25 KB
    // ~61.5 KB

    const int t   = threadIdx.x;
    const int l   = t & 63;
    const int g   = t >> 6;        // wave id = channel group
    const int sub = l >> 4;        // channel subgroup 0..3
    const int l16 = l & 15;
    const int w0  = l16 * 4;       // first pixel column of this lane

    // XCD-aware swizzle: XCD x owns rows [x*8, x*8+8) for all batches.
    const int n    = blockIdx.x + gridDim.x * blockIdx.y;
    const int slot = n >> 3;
    const int h = (n & 7) * 8 + (slot & 7);
    const int b = slot >> 3;

    const int hm = (h > 0) ? (h - 1) : 0;
    const int hp = (h < H_ - 1) ? (h + 1) : (H_ - 1);
    const size_t cs = (size_t)H_ * W_;
    const int c0 = g * CPG;

    for (int i = t; i < 2 * C_; i += NT) lds_cw[i] = cw[i];
    if (t < 3 * W_) {
        const int r = t >> 6, col = t & 63;
        const int row = (r == 0) ? hm : ((r == 1) ? h : hp);
        lds_msk[r][col] = mask[((size_t)b * H_ + row) * W_ + col];
    }
    __syncthreads();

    const size_t base = (size_t)(b * C_ + c0) * H_;
    const size_t lo   = (size_t)sub * cs + w0;
    const float* ftp = Ft  + (base + h ) * W_ + lo;
    const float* q0p = Fwp + (base + hm) * W_ + lo;
    const float* q1p = Fwp + (base + h ) * W_ + lo;
    const float* q2p = Fwp + (base + hp) * W_ + lo;

    // ---- Pass A + P/T fused: ONE streaming walk ---------------------------
    float acc[36], Pp[12], T4[4];
    #pragma unroll
    for (int i = 0; i < 36; ++i) acc[i] = 0.f;
    #pragma unroll
    for (int i = 0; i < 12; ++i) Pp[i] = 0.f;
    #pragma unroll
    for (int i = 0; i < 4; ++i) T4[i] = 0.f;

    #pragma unroll 4
    for (int k = 0; k < CPG; k += 4) {
        const size_t off = (size_t)k * cs;
        const float4 ft4 = *(const float4*)(ftp + off);
        const float4 r0  = *(const float4*)(q0p + off);
        const float4 r1  = *(const float4*)(q1p + off);
        const float4 r2  = *(const float4*)(q2p + off);
        row_acc(ft4, r0, l16, &acc[0]);
        row_acc(ft4, r1, l16, &acc[12]);
        row_acc(ft4, r2, l16, &acc[24]);
        const int c = c0 + k + sub;
        const float wF = lds_cw[c];
        const float wT = lds_cw[C_ + c];
        Pp[0] = fmaf(wF, r0.x, Pp[0]); Pp[1]  = fmaf(wF, r0.y, Pp[1]);
        Pp[2] = fmaf(wF, r0.z, Pp[2]); Pp[3]  = fmaf(wF, r0.w, Pp[3]);
        Pp[4] = fmaf(wF, r1.x, Pp[4]); Pp[5]  = fmaf(wF, r1.y, Pp[5]);
        Pp[6] = fmaf(wF, r1.z, Pp[6]); Pp[7]  = fmaf(wF, r1.w, Pp[7]);
        Pp[8] = fmaf(wF, r2.x, Pp[8]); Pp[9]  = fmaf(wF, r2.y, Pp[9]);
        Pp[10]= fmaf(wF, r2.z, Pp[10]);Pp[11] = fmaf(wF, r2.w, Pp[11]);
        T4[0] = fmaf(wT, ft4.x, T4[0]); T4[1] = fmaf(wT, ft4.y, T4[1]);
        T4[2] = fmaf(wT, ft4.z, T4[2]); T4[3] = fmaf(wT, ft4.w, T4[3]);
    }

    // reduce the 4 channel-subgroups (lanes l, l^16, l^32, l^48)
    #pragma unroll
    for (int i = 0; i < 36; ++i) {
        acc[i] += __shfl_xor(acc[i], 16, 64);
        acc[i] += __shfl_xor(acc[i], 32, 64);
    }
    #pragma unroll
    for (int i = 0; i < 12; ++i) {
        Pp[i] += __shfl_xor(Pp[i], 16, 64);
        Pp[i] += __shfl_xor(Pp[i], 32, 64);
    }
    #pragma unroll
    for (int i = 0; i < 4; ++i) {
        T4[i] += __shfl_xor(T4[i], 16, 64);
        T4[i] += __shfl_xor(T4[i], 32, 64);
    }

    // STATIC-index LDS write (rule #20: px is an unroll constant)
    if (l < 16) {
        #pragma unroll
        for (int px = 0; px < 4; ++px) {
            #pragma unroll
            for (int r = 0; r < 3; ++r) {
                #pragma unroll
                for (int cc = 0; cc < 3; ++cc)
                    lds_sim[g][w0 + px][r * 3 + cc] = acc[r * 12 + cc * 4 + px];
                lds_PT[g][r][w0 + px] = Pp[r * 4 + px];
            }
            lds_PT[g][3][w0 + px] = T4[px];
        }
    }
    __syncthreads();

    // ---- reduce across waves + mask; P/T reduce in parallel threads -------
    if (t < W_ * 9) {
        const int ww = t / 9, q = t % 9;
        float s = 0.f;
        #pragma unroll
        for (int gg = 0; gg < G_; ++gg) s += lds_sim[gg][ww][q];
        s *= 0.03952847075210474f;          // 1/sqrt(640)
        const int r = q / 3, j = q % 3;
        int col = ww + j - 1;
        col = col < 0 ? 0 : (col > W_ - 1 ? W_ - 1 : col);
        if (lds_msk[r][col] == 1.0f) s = -1e9f;
        lds_attn[ww][q] = s;
    } else if (t >= 640 && t < 640 + 256) {
        const int idx = t - 640;
        const int r = idx >> 6, ww = idx & 63;
        float s = 0.f;
        #pragma unroll
        for (int gg = 0; gg < G_; ++gg) s += lds_PT[gg][r][ww];
        lds_Pf[r][ww] = s;
    }
    __syncthreads();

    // ---- softmax per pixel + lambda via P-trick ---------------------------
    if (t < W_) {
        float v[9];
        float mx = -3e38f;
        bool valid = false;
        #pragma unroll
        for (int q = 0; q < 9; ++q) {
            v[q] = lds_attn[t][q];
            if (v[q] > -5e8f) valid = true;
            mx = fmaxf(mx, v[q]);
        }
        float a9[9];
        if (!valid) {
            #pragma unroll
            for (int q = 0; q < 9; ++q) a9[q] = 0.f;
        } else {
            float sum = 0.f;
            #pragma unroll
            for (int q = 0; q < 9; ++q) { a9[q] = expf(v[q] - mx); sum += a9[q]; }
            const float inv = 1.f / sum;
            #pragma unroll
            for (int q = 0; q < 9; ++q) a9[q] *= inv;
        }
        #pragma unroll
        for (int q = 0; q < 9; ++q) lds_attn[t][q] = a9[q];

        float lamF = 0.f;
        #pragma unroll
        for (int r = 0; r < 3; ++r)
            #pragma unroll
            for (int j = 0; j < 3; ++j) {
                int col = t + j - 1;
                col = col < 0 ? 0 : (col > W_ - 1 ? W_ - 1 : col);
                lamF = fmaf(a9[r * 3 + j], lds_Pf[r][col], lamF);
            }
        const float d = lds_Pf[3][t] + lamF + cb[0];
        lds_lam[t] = 1.f / (1.f + expf(-d));
    }
    __syncthreads();

    // ---- Pass BC: fwv + blend + store (reverse order: tail still in L2) ---
    float at[36];
    #pragma unroll
    for (int px = 0; px < 4; ++px)
        #pragma unroll
        for (int q = 0; q < 9; ++q) at[px * 9 + q] = lds_attn[w0 + px][q];
    float lam4[4], oml4[4];
    #pragma unroll
    for (int px = 0; px < 4; ++px) {
        lam4[px] = lds_lam[w0 + px];
        oml4[px] = 1.f - lam4[px];
    }

    float* outp = out + (base + h) * W_ + lo;
    #pragma unroll 4
    for (int kk = 0; kk < CPG; kk += 4) {
        const int k = CPG - 4 - kk;          // reverse walk (LIFO L2 reuse)
        const size_t off = (size_t)k * cs;
        const float4 ft4 = *(const float4*)(ftp + off);
        const float4 r0  = *(const float4*)(q0p + off);
        const float4 r1  = *(const float4*)(q1p + off);
        const float4 r2  = *(const float4*)(q2p + off);
        float fwv[4] = {0.f, 0.f, 0.f, 0.f};
        row_fw(r0, l16, at, 0, fwv);
        row_fw(r1, l16, at, 3, fwv);
        row_fw(r2, l16, at, 6, fwv);
        float4 o;
        o.x = lam4[0] * ft4.x + oml4[0] * fwv[0];
        o.y = lam4[1] * ft4.y + oml4[1] * fwv[1];
        o.z = lam4[2] * ft4.z + oml4[2] * fwv[2];
        o.w = lam4[3] * ft4.w + oml4[3] * fwv[3];
        *(float4*)(outp + off) = o;
    }
}

extern "C" void kernel_launch(void* const* d_in, const int* in_sizes, int n_in,
                              void* d_out, int out_size, void* d_ws, size_t ws_size,
                              hipStream_t stream) {
    const float* Ft   = (const float*)d_in[0];
    const float* Fwp  = (const float*)d_in[1];
    const float* mask = (const float*)d_in[2];
    const float* cw   = (const float*)d_in[3];
    const float* cb   = (const float*)d_in[4];
    float* out = (float*)d_out;

    dim3 grid(H_, B_);   // 256 blocks == 256 CUs
    dim3 block(NT);
    nca_fused<<<grid, block, 0, stream>>>(Ft, Fwp, mask, cw, cb, out);
}

// Round 17
// 46.460 us; speedup vs baseline: 4.0975x; 1.1376x over previous
//
#include <hip/hip_runtime.h>
#include <hip/hip_bf16.h>

#define B_  4
#define C_  640
#define H_  64
#define W_  64
#define G_  16          // channel groups (one wave each)
#define CPG 40          // channels per wave: G_*CPG == C_
#define NT  1024
#define F1S 66          // lds_f1 row stride (ushorts): bank-spread padding

__device__ __forceinline__ unsigned short f2bf(float f) {
    __hip_bfloat16 h = __float2bfloat16(f);
    return __builtin_bit_cast(unsigned short, h);
}

// Accumulate one Fwarp row (4 px in r) against ft4 into a[12] (3 col-offsets x 4 px).
__device__ __forceinline__ void row_acc(const float4 ft4, const float4 r,
                                        const int l16, float* a) {
    const float pw = __shfl_up(r.w, 1, 64);     // lane l-1's elem 3
    const float nx = __shfl_down(r.x, 1, 64);   // lane l+1's elem 0
    const float vL0 = (l16 == 0)  ? r.x : pw;   // col 0 replicate
    const float vR3 = (l16 == 15) ? r.w : nx;   // col 63 replicate
    a[0]  = fmaf(ft4.x, vL0, a[0]);             // cc = col-1
    a[1]  = fmaf(ft4.y, r.x, a[1]);
    a[2]  = fmaf(ft4.z, r.y, a[2]);
    a[3]  = fmaf(ft4.w, r.z, a[3]);
    a[4]  = fmaf(ft4.x, r.x, a[4]);             // cc = center
    a[5]  = fmaf(ft4.y, r.y, a[5]);
    a[6]  = fmaf(ft4.z, r.z, a[6]);
    a[7]  = fmaf(ft4.w, r.w, a[7]);
    a[8]  = fmaf(ft4.x, r.y, a[8]);             // cc = col+1
    a[9]  = fmaf(ft4.y, r.z, a[9]);
    a[10] = fmaf(ft4.z, r.w, a[10]);
    a[11] = fmaf(ft4.w, vR3, a[11]);
}

// Weighted sum of one Fwarp row into fwv[4]; at = attn[4px][9], r3 = 3*row.
__device__ __forceinline__ void row_fw(const float4 r, const int l16,
                                       const float* at, const int r3, float* fwv) {
    const float pw = __shfl_up(r.w, 1, 64);
    const float nx = __shfl_down(r.x, 1, 64);
    const float vL0 = (l16 == 0)  ? r.x : pw;
    const float vR3 = (l16 == 15) ? r.w : nx;
    fwv[0] += at[0*9+r3]*vL0 + at[0*9+r3+1]*r.x + at[0*9+r3+2]*r.y;
    fwv[1] += at[1*9+r3]*r.x + at[1*9+r3+1]*r.y + at[1*9+r3+2]*r.z;
    fwv[2] += at[2*9+r3]*r.y + at[2*9+r3+1]*r.z + at[2*9+r3+2]*r.w;
    fwv[3] += at[3*9+r3]*r.z + at[3*9+r3+1]*r.w + at[3*9+r3+2]*vR3;
}

__global__ __launch_bounds__(NT, 4) void nca_fused(
    const float* __restrict__ Ft,
    const float* __restrict__ Fwp,
    const float* __restrict__ mask,
    const float* __restrict__ cw,
    const float* __restrict__ cb,
    float* __restrict__ out)
{
    __shared__ float lds_cw[2 * C_];            // 5 KB
    __shared__ float lds_msk[3][W_];            // 0.75 KB
    __shared__ float lds_sim[G_][W_][9];        // 36 KB
    __shared__ float lds_PT[G_][4][W_];         // 16 KB
    __shared__ float lds_attn[W_][9];           // 2.25 KB
    __shared__ float lds_Pf[4][W_];             // 1 KB
    __shared__ float lds_lam[W_];               // 0.25 KB
    __shared__ unsigned short lds_f1[C_][F1S];  // 82.5 KB  center Fwarp row, bf16
    // total ~144 KB (< 160 KB/CU, 1 block/CU)

    const int t   = threadIdx.x;
    const int l   = t & 63;
    const int g   = t >> 6;        // wave id = channel group
    const int sub = l >> 4;        // channel subgroup 0..3
    const int l16 = l & 15;
    const int w0  = l16 * 4;       // first pixel column of this lane

    // XCD-aware swizzle: XCD x owns rows [x*8, x*8+8) for all batches.
    const int n    = blockIdx.x + gridDim.x * blockIdx.y;
    const int slot = n >> 3;
    const int h = (n & 7) * 8 + (slot & 7);
    const int b = slot >> 3;

    const int hm = (h > 0) ? (h - 1) : 0;
    const int hp = (h < H_ - 1) ? (h + 1) : (H_ - 1);
    const size_t cs = (size_t)H_ * W_;
    const int c0 = g * CPG;

    for (int i = t; i < 2 * C_; i += NT) lds_cw[i] = cw[i];
    if (t < 3 * W_) {
        const int r = t >> 6, col = t & 63;
        const int row = (r == 0) ? hm : ((r == 1) ? h : hp);
        lds_msk[r][col] = mask[((size_t)b * H_ + row) * W_ + col];
    }
    __syncthreads();

    const size_t base = (size_t)(b * C_ + c0) * H_;
    const size_t lo   = (size_t)sub * cs + w0;
    const float* ftp = Ft  + (base + h ) * W_ + lo;
    const float* q0p = Fwp + (base + hm) * W_ + lo;
    const float* q1p = Fwp + (base + h ) * W_ + lo;
    const float* q2p = Fwp + (base + hp) * W_ + lo;

    // ---- Pass A + P/T fused: ONE streaming walk; stash f1 -> LDS (bf16) ---
    float acc[36], Pp[12], T4[4];
    #pragma unroll
    for (int i = 0; i < 36; ++i) acc[i] = 0.f;
    #pragma unroll
    for (int i = 0; i < 12; ++i) Pp[i] = 0.f;
    #pragma unroll
    for (int i = 0; i < 4; ++i) T4[i] = 0.f;

    #pragma unroll 4
    for (int k = 0; k < CPG; k += 4) {
        const size_t off = (size_t)k * cs;
        const float4 ft4 = *(const float4*)(ftp + off);
        const float4 r0  = *(const float4*)(q0p + off);
        const float4 r1  = *(const float4*)(q1p + off);
        const float4 r2  = *(const float4*)(q2p + off);
        row_acc(ft4, r0, l16, &acc[0]);
        row_acc(ft4, r1, l16, &acc[12]);
        row_acc(ft4, r2, l16, &acc[24]);
        // stash center row for Pass BC (no live registers across phases)
        ushort4 us;
        us.x = f2bf(r1.x); us.y = f2bf(r1.y);
        us.z = f2bf(r1.z); us.w = f2bf(r1.w);
        *(ushort4*)(&lds_f1[c0 + k + sub][w0]) = us;
        const int c = c0 + k + sub;
        const float wF = lds_cw[c];
        const float wT = lds_cw[C_ + c];
        Pp[0] = fmaf(wF, r0.x, Pp[0]); Pp[1]  = fmaf(wF, r0.y, Pp[1]);
        Pp[2] = fmaf(wF, r0.z, Pp[2]); Pp[3]  = fmaf(wF, r0.w, Pp[3]);
        Pp[4] = fmaf(wF, r1.x, Pp[4]); Pp[5]  = fmaf(wF, r1.y, Pp[5]);
        Pp[6] = fmaf(wF, r1.z, Pp[6]); Pp[7]  = fmaf(wF, r1.w, Pp[7]);
        Pp[8] = fmaf(wF, r2.x, Pp[8]); Pp[9]  = fmaf(wF, r2.y, Pp[9]);
        Pp[10]= fmaf(wF, r2.z, Pp[10]);Pp[11] = fmaf(wF, r2.w, Pp[11]);
        T4[0] = fmaf(wT, ft4.x, T4[0]); T4[1] = fmaf(wT, ft4.y, T4[1]);
        T4[2] = fmaf(wT, ft4.z, T4[2]); T4[3] = fmaf(wT, ft4.w, T4[3]);
    }

    // reduce the 4 channel-subgroups (lanes l, l^16, l^32, l^48)
    #pragma unroll
    for (int i = 0; i < 36; ++i) {
        acc[i] += __shfl_xor(acc[i], 16, 64);
        acc[i] += __shfl_xor(acc[i], 32, 64);
    }
    #pragma unroll
    for (int i = 0; i < 12; ++i) {
        Pp[i] += __shfl_xor(Pp[i], 16, 64);
        Pp[i] += __shfl_xor(Pp[i], 32, 64);
    }
    #pragma unroll
    for (int i = 0; i < 4; ++i) {
        T4[i] += __shfl_xor(T4[i], 16, 64);
        T4[i] += __shfl_xor(T4[i], 32, 64);
    }

    // STATIC-index LDS write (rule #20: px is an unroll constant)
    if (l < 16) {
        #pragma unroll
        for (int px = 0; px < 4; ++px) {
            #pragma unroll
            for (int r = 0; r < 3; ++r) {
                #pragma unroll
                for (int cc = 0; cc < 3; ++cc)
                    lds_sim[g][w0 + px][r * 3 + cc] = acc[r * 12 + cc * 4 + px];
                lds_PT[g][r][w0 + px] = Pp[r * 4 + px];
            }
            lds_PT[g][3][w0 + px] = T4[px];
        }
    }
    __syncthreads();

    // ---- reduce across waves + mask; P/T reduce in parallel threads -------
    if (t < W_ * 9) {
        const int ww = t / 9, q = t % 9;
        float s = 0.f;
        #pragma unroll
        for (int gg = 0; gg < G_; ++gg) s += lds_sim[gg][ww][q];
        s *= 0.03952847075210474f;          // 1/sqrt(640)
        const int r = q / 3, j = q % 3;
        int col = ww + j - 1;
        col = col < 0 ? 0 : (col > W_ - 1 ? W_ - 1 : col);
        if (lds_msk[r][col] == 1.0f) s = -1e9f;
        lds_attn[ww][q] = s;
    } else if (t >= 640 && t < 640 + 256) {
        const int idx = t - 640;
        const int r = idx >> 6, ww = idx & 63;
        float s = 0.f;
        #pragma unroll
        for (int gg = 0; gg < G_; ++gg) s += lds_PT[gg][r][ww];
        lds_Pf[r][ww] = s;
    }
    __syncthreads();

    // ---- softmax per pixel + lambda via P-trick ---------------------------
    if (t < W_) {
        float v[9];
        float mx = -3e38f;
        bool valid = false;
        #pragma unroll
        for (int q = 0; q < 9; ++q) {
            v[q] = lds_attn[t][q];
            if (v[q] > -5e8f) valid = true;
            mx = fmaxf(mx, v[q]);
        }
        float a9[9];
        if (!valid) {
            #pragma unroll
            for (int q = 0; q < 9; ++q) a9[q] = 0.f;
        } else {
            float sum = 0.f;
            #pragma unroll
            for (int q = 0; q < 9; ++q) { a9[q] = expf(v[q] - mx); sum += a9[q]; }
            const float inv = 1.f / sum;
            #pragma unroll
            for (int q = 0; q < 9; ++q) a9[q] *= inv;
        }
        #pragma unroll
        for (int q = 0; q < 9; ++q) lds_attn[t][q] = a9[q];

        float lamF = 0.f;
        #pragma unroll
        for (int r = 0; r < 3; ++r)
            #pragma unroll
            for (int j = 0; j < 3; ++j) {
                int col = t + j - 1;
                col = col < 0 ? 0 : (col > W_ - 1 ? W_ - 1 : col);
                lamF = fmaf(a9[r * 3 + j], lds_Pf[r][col], lamF);
            }
        const float d = lds_Pf[3][t] + lamF + cb[0];
        lds_lam[t] = 1.f / (1.f + expf(-d));
    }
    __syncthreads();

    // ---- Pass BC: fwv + blend + store (3 global streams + LDS f1) ---------
    float at[36];
    #pragma unroll
    for (int px = 0; px < 4; ++px)
        #pragma unroll
        for (int q = 0; q < 9; ++q) at[px * 9 + q] = lds_attn[w0 + px][q];
    float lam4[4], oml4[4];
    #pragma unroll
    for (int px = 0; px < 4; ++px) {
        lam4[px] = lds_lam[w0 + px];
        oml4[px] = 1.f - lam4[px];
    }

    float* outp = out + (base + h) * W_ + lo;
    #pragma unroll 2
    for (int k = 0; k < CPG; k += 4) {
        const size_t off = (size_t)k * cs;
        const float4 ft4 = *(const float4*)(ftp + off);
        const float4 r0  = *(const float4*)(q0p + off);
        const float4 r2  = *(const float4*)(q2p + off);
        const ushort4 us = *(const ushort4*)(&lds_f1[c0 + k + sub][w0]);
        float4 r1;
        r1.x = __builtin_bit_cast(float, (unsigned)us.x << 16);
        r1.y = __builtin_bit_cast(float, (unsigned)us.y << 16);
        r1.z = __builtin_bit_cast(float, (unsigned)us.z << 16);
        r1.w = __builtin_bit_cast(float, (unsigned)us.w << 16);
        float fwv[4] = {0.f, 0.f, 0.f, 0.f};
        row_fw(r0, l16, at, 0, fwv);
        row_fw(r1, l16, at, 3, fwv);
        row_fw(r2, l16, at, 6, fwv);
        float4 o;
        o.x = lam4[0] * ft4.x + oml4[0] * fwv[0];
        o.y = lam4[1] * ft4.y + oml4[1] * fwv[1];
        o.z = lam4[2] * ft4.z + oml4[2] * fwv[2];
        o.w = lam4[3] * ft4.w + oml4[3] * fwv[3];
        *(float4*)(outp + off) = o;
    }
}

extern "C" void kernel_launch(void* const* d_in, const int* in_sizes, int n_in,
                              void* d_out, int out_size, void* d_ws, size_t ws_size,
                              hipStream_t stream) {
    const float* Ft   = (const float*)d_in[0];
    const float* Fwp  = (const float*)d_in[1];
    const float* mask = (const float*)d_in[2];
    const float* cw   = (const float*)d_in[3];
    const float* cb   = (const float*)d_in[4];
    float* out = (float*)d_out;

    dim3 grid(H_, B_);   // 256 blocks == 256 CUs
    dim3 block(NT);
    nca_fused<<<grid, block, 0, stream>>>(Ft, Fwp, mask, cw, cb, out);
}

// Round 18
// 41.331 us; speedup vs baseline: 4.6060x; 1.1241x over previous
//
#include <hip/hip_runtime.h>
#include <hip/hip_bf16.h>

#define B_  4
#define C_  640
#define H_  64
#define W_  64
#define G_  16          // channel groups (one wave each)
#define CPG 40          // channels per wave: G_*CPG == C_
#define NT  1024
#define GRP 66          // group-dim stride (uints): 64 groups + 2 pad

__device__ __forceinline__ unsigned short f2bf(float f) {
    __hip_bfloat16 h = __float2bfloat16(f);
    return __builtin_bit_cast(unsigned short, h);
}
__device__ __forceinline__ unsigned int packbf(float a, float b) {
    return (unsigned)f2bf(a) | ((unsigned)f2bf(b) << 16);
}
__device__ __forceinline__ float lo16(unsigned u) {
    return __builtin_bit_cast(float, u << 16);
}
__device__ __forceinline__ float hi16(unsigned u) {
    return __builtin_bit_cast(float, u & 0xffff0000u);
}

// Accumulate one Fwarp row (4 px in r) against ft4 into a[12] (3 col-offsets x 4 px).
__device__ __forceinline__ void row_acc(const float4 ft4, const float4 r,
                                        const int l16, float* a) {
    const float pw = __shfl_up(r.w, 1, 64);     // lane l-1's elem 3
    const float nx = __shfl_down(r.x, 1, 64);   // lane l+1's elem 0
    const float vL0 = (l16 == 0)  ? r.x : pw;   // col 0 replicate
    const float vR3 = (l16 == 15) ? r.w : nx;   // col 63 replicate
    a[0]  = fmaf(ft4.x, vL0, a[0]);             // cc = col-1
    a[1]  = fmaf(ft4.y, r.x, a[1]);
    a[2]  = fmaf(ft4.z, r.y, a[2]);
    a[3]  = fmaf(ft4.w, r.z, a[3]);
    a[4]  = fmaf(ft4.x, r.x, a[4]);             // cc = center
    a[5]  = fmaf(ft4.y, r.y, a[5]);
    a[6]  = fmaf(ft4.z, r.z, a[6]);
    a[7]  = fmaf(ft4.w, r.w, a[7]);
    a[8]  = fmaf(ft4.x, r.y, a[8]);             // cc = col+1
    a[9]  = fmaf(ft4.y, r.z, a[9]);
    a[10] = fmaf(ft4.z, r.w, a[10]);
    a[11] = fmaf(ft4.w, vR3, a[11]);
}

// Weighted sum of one Fwarp row into fwv[4]; at = attn[4px][9], r3 = 3*row.
__device__ __forceinline__ void row_fw(const float4 r, const int l16,
                                       const float* at, const int r3, float* fwv) {
    const float pw = __shfl_up(r.w, 1, 64);
    const float nx = __shfl_down(r.x, 1, 64);
    const float vL0 = (l16 == 0)  ? r.x : pw;
    const float vR3 = (l16 == 15) ? r.w : nx;
    fwv[0] += at[0*9+r3]*vL0 + at[0*9+r3+1]*r.x + at[0*9+r3+2]*r.y;
    fwv[1] += at[1*9+r3]*r.x + at[1*9+r3+1]*r.y + at[1*9+r3+2]*r.z;
    fwv[2] += at[2*9+r3]*r.y + at[2*9+r3+1]*r.z + at[2*9+r3+2]*r.w;
    fwv[3] += at[3*9+r3]*r.z + at[3*9+r3+1]*r.w + at[3*9+r3+2]*vR3;
}

__global__ __launch_bounds__(NT, 4) void nca_fused(
    const float* __restrict__ Ft,
    const float* __restrict__ Fwp,
    const float* __restrict__ mask,
    const float* __restrict__ cw,
    const float* __restrict__ cb,
    float* __restrict__ out)
{
    __shared__ float lds_cw[2 * C_];            // 5 KB
    __shared__ float lds_msk[3][W_];            // 0.75 KB
    __shared__ unsigned int lds_simb[9][32][GRP]; // 74.25 KB  bf16-pair sim partials
    __shared__ unsigned int lds_PTb[4][32][GRP];  // 33 KB     bf16-pair P/T partials
    __shared__ float lds_attn[W_][9];           // 2.25 KB
    __shared__ float lds_Pf[4][W_];             // 1 KB
    __shared__ float lds_lam[W_];               // 0.25 KB
    // total ~116.5 KB (< 160 KB/CU, 1 block/CU)

    const int t   = threadIdx.x;
    const int l   = t & 63;
    const int g   = t >> 6;        // wave id = channel group
    const int sub = l >> 4;        // channel subgroup 0..3
    const int l16 = l & 15;
    const int w0  = l16 * 4;       // first pixel column of this lane

    // XCD-aware swizzle: XCD x owns rows [x*8, x*8+8) for all batches.
    const int n    = blockIdx.x + gridDim.x * blockIdx.y;
    const int slot = n >> 3;
    const int h = (n & 7) * 8 + (slot & 7);
    const int b = slot >> 3;

    const int hm = (h > 0) ? (h - 1) : 0;
    const int hp = (h < H_ - 1) ? (h + 1) : (H_ - 1);
    const size_t cs = (size_t)H_ * W_;
    const int c0 = g * CPG;

    for (int i = t; i < 2 * C_; i += NT) lds_cw[i] = cw[i];
    if (t < 3 * W_) {
        const int r = t >> 6, col = t & 63;
        const int row = (r == 0) ? hm : ((r == 1) ? h : hp);
        lds_msk[r][col] = mask[((size_t)b * H_ + row) * W_ + col];
    }
    __syncthreads();

    const size_t base = (size_t)(b * C_ + c0) * H_;
    const size_t lo   = (size_t)sub * cs + w0;
    const float* ftp = Ft  + (base + h ) * W_ + lo;
    const float* q0p = Fwp + (base + hm) * W_ + lo;
    const float* q1p = Fwp + (base + h ) * W_ + lo;
    const float* q2p = Fwp + (base + hp) * W_ + lo;

    // ---- Pass A + P/T fused: ONE streaming walk ---------------------------
    float acc[36], Pp[12], T4[4];
    #pragma unroll
    for (int i = 0; i < 36; ++i) acc[i] = 0.f;
    #pragma unroll
    for (int i = 0; i < 12; ++i) Pp[i] = 0.f;
    #pragma unroll
    for (int i = 0; i < 4; ++i) T4[i] = 0.f;

    #pragma unroll 4
    for (int k = 0; k < CPG; k += 4) {
        const size_t off = (size_t)k * cs;
        const float4 ft4 = *(const float4*)(ftp + off);
        const float4 r0  = *(const float4*)(q0p + off);
        const float4 r1  = *(const float4*)(q1p + off);
        const float4 r2  = *(const float4*)(q2p + off);
        row_acc(ft4, r0, l16, &acc[0]);
        row_acc(ft4, r1, l16, &acc[12]);
        row_acc(ft4, r2, l16, &acc[24]);
        const int c = c0 + k + sub;
        const float wF = lds_cw[c];
        const float wT = lds_cw[C_ + c];
        Pp[0] = fmaf(wF, r0.x, Pp[0]); Pp[1]  = fmaf(wF, r0.y, Pp[1]);
        Pp[2] = fmaf(wF, r0.z, Pp[2]); Pp[3]  = fmaf(wF, r0.w, Pp[3]);
        Pp[4] = fmaf(wF, r1.x, Pp[4]); Pp[5]  = fmaf(wF, r1.y, Pp[5]);
        Pp[6] = fmaf(wF, r1.z, Pp[6]); Pp[7]  = fmaf(wF, r1.w, Pp[7]);
        Pp[8] = fmaf(wF, r2.x, Pp[8]); Pp[9]  = fmaf(wF, r2.y, Pp[9]);
        Pp[10]= fmaf(wF, r2.z, Pp[10]);Pp[11] = fmaf(wF, r2.w, Pp[11]);
        T4[0] = fmaf(wT, ft4.x, T4[0]); T4[1] = fmaf(wT, ft4.y, T4[1]);
        T4[2] = fmaf(wT, ft4.z, T4[2]); T4[3] = fmaf(wT, ft4.w, T4[3]);
    }

    // ---- NO butterfly: pack bf16 pairs, direct conflict-free LDS writes ---
    // Write op (q,pp): bank = (4*l16 + sub) % 32 -> all 32 banks, 2-way (free).
    // All 64 channel-groups (g*4+sub) reduced later in the parallel phase.
    {
        const int g4s = g * 4 + sub;        // channel-group 0..63
        #pragma unroll
        for (int q = 0; q < 9; ++q) {
            lds_simb[q][2 * l16 + 0][g4s] = packbf(acc[q * 4 + 0], acc[q * 4 + 1]);
            lds_simb[q][2 * l16 + 1][g4s] = packbf(acc[q * 4 + 2], acc[q * 4 + 3]);
        }
        #pragma unroll
        for (int r = 0; r < 3; ++r) {
            lds_PTb[r][2 * l16 + 0][g4s] = packbf(Pp[r * 4 + 0], Pp[r * 4 + 1]);
            lds_PTb[r][2 * l16 + 1][g4s] = packbf(Pp[r * 4 + 2], Pp[r * 4 + 3]);
        }
        lds_PTb[3][2 * l16 + 0][g4s] = packbf(T4[0], T4[1]);
        lds_PTb[3][2 * l16 + 1][g4s] = packbf(T4[2], T4[3]);
    }
    __syncthreads();

    // ---- reduce 64 groups + mask (288 thr) ; P/T reduce (128 thr) ---------
    if (t < 288) {
        const int q = t / 32, wp = t % 32;        // ww pair (2wp, 2wp+1)
        float s0 = 0.f, s1 = 0.f;
        #pragma unroll
        for (int i = 0; i < 32; ++i) {
            const uint2 u = *(const uint2*)&lds_simb[q][wp][2 * i];
            s0 += lo16(u.x) + lo16(u.y);
            s1 += hi16(u.x) + hi16(u.y);
        }
        s0 *= 0.03952847075210474f;               // 1/sqrt(640)
        s1 *= 0.03952847075210474f;
        const int r = q / 3, j = q % 3;
        const int ww0 = 2 * wp, ww1 = 2 * wp + 1;
        int cA = ww0 + j - 1; cA = cA < 0 ? 0 : (cA > W_ - 1 ? W_ - 1 : cA);
        int cB = ww1 + j - 1; cB = cB < 0 ? 0 : (cB > W_ - 1 ? W_ - 1 : cB);
        if (lds_msk[r][cA] == 1.0f) s0 = -1e9f;
        if (lds_msk[r][cB] == 1.0f) s1 = -1e9f;
        lds_attn[ww0][q] = s0;
        lds_attn[ww1][q] = s1;
    } else if (t < 288 + 128) {
        const int idx = t - 288;
        const int r = idx / 32, wp = idx % 32;
        float s0 = 0.f, s1 = 0.f;
        #pragma unroll
        for (int i = 0; i < 32; ++i) {
            const uint2 u = *(const uint2*)&lds_PTb[r][wp][2 * i];
            s0 += lo16(u.x) + lo16(u.y);
            s1 += hi16(u.x) + hi16(u.y);
        }
        lds_Pf[r][2 * wp]     = s0;
        lds_Pf[r][2 * wp + 1] = s1;
    }
    __syncthreads();

    // ---- softmax per pixel + lambda via P-trick ---------------------------
    if (t < W_) {
        float v[9];
        float mx = -3e38f;
        bool valid = false;
        #pragma unroll
        for (int q = 0; q < 9; ++q) {
            v[q] = lds_attn[t][q];
            if (v[q] > -5e8f) valid = true;
            mx = fmaxf(mx, v[q]);
        }
        float a9[9];
        if (!valid) {
            #pragma unroll
            for (int q = 0; q < 9; ++q) a9[q] = 0.f;
        } else {
            float sum = 0.f;
            #pragma unroll
            for (int q = 0; q < 9; ++q) { a9[q] = expf(v[q] - mx); sum += a9[q]; }
            const float inv = 1.f / sum;
            #pragma unroll
            for (int q = 0; q < 9; ++q) a9[q] *= inv;
        }
        #pragma unroll
        for (int q = 0; q < 9; ++q) lds_attn[t][q] = a9[q];

        float lamF = 0.f;
        #pragma unroll
        for (int r = 0; r < 3; ++r)
            #pragma unroll
            for (int j = 0; j < 3; ++j) {
                int col = t + j - 1;
                col = col < 0 ? 0 : (col > W_ - 1 ? W_ - 1 : col);
                lamF = fmaf(a9[r * 3 + j], lds_Pf[r][col], lamF);
            }
        const float d = lds_Pf[3][t] + lamF + cb[0];
        lds_lam[t] = 1.f / (1.f + expf(-d));
    }
    __syncthreads();

    // ---- Pass BC: fwv + blend + store (ONE walk, streams cache-warm) ------
    float at[36];
    #pragma unroll
    for (int px = 0; px < 4; ++px)
        #pragma unroll
        for (int q = 0; q < 9; ++q) at[px * 9 + q] = lds_attn[w0 + px][q];
    float lam4[4], oml4[4];
    #pragma unroll
    for (int px = 0; px < 4; ++px) {
        lam4[px] = lds_lam[w0 + px];
        oml4[px] = 1.f - lam4[px];
    }

    float* outp = out + (base + h) * W_ + lo;
    #pragma unroll 2
    for (int k = 0; k < CPG; k += 4) {
        const size_t off = (size_t)k * cs;
        const float4 ft4 = *(const float4*)(ftp + off);
        const float4 r0  = *(const float4*)(q0p + off);
        const float4 r1  = *(const float4*)(q1p + off);
        const float4 r2  = *(const float4*)(q2p + off);
        float fwv[4] = {0.f, 0.f, 0.f, 0.f};
        row_fw(r0, l16, at, 0, fwv);
        row_fw(r1, l16, at, 3, fwv);
        row_fw(r2, l16, at, 6, fwv);
        float4 o;
        o.x = lam4[0] * ft4.x + oml4[0] * fwv[0];
        o.y = lam4[1] * ft4.y + oml4[1] * fwv[1];
        o.z = lam4[2] * ft4.z + oml4[2] * fwv[2];
        o.w = lam4[3] * ft4.w + oml4[3] * fwv[3];
        *(float4*)(outp + off) = o;
    }
}

extern "C" void kernel_launch(void* const* d_in, const int* in_sizes, int n_in,
                              void* d_out, int out_size, void* d_ws, size_t ws_size,
                              hipStream_t stream) {
    const float* Ft   = (const float*)d_in[0];
    const float* Fwp  = (const float*)d_in[1];
    const float* mask = (const float*)d_in[2];
    const float* cw   = (const float*)d_in[3];
    const float* cb   = (const float*)d_in[4];
    float* out = (float*)d_out;

    dim3 grid(H_, B_);   // 256 blocks == 256 CUs
    dim3 block(NT);
    nca_fused<<<grid, block, 0, stream>>>(Ft, Fwp, mask, cw, cb, out);
}